// Round 17
// baseline (66.783 us; speedup 1.0000x reference)
//
#include <hip/hip_runtime.h>

// SSIM fused: [16,1,1024,1024] fp32, 11-tap separable Gaussian.
// BARRIER-FREE wave-private tiles, repacked into 512-thread blocks:
// 8 waves x 8 KB private LDS slabs (64 KB/block) — blocks are atomic
// residency units, so this forces >=8-wave granularity per CU (tests the
// "2 blocks/CU" residency-cap hypothesis from r7-r12's flat ~23% occupancy).
// Per wave: 64-col x 32-row tile; V-blur register ring of 11 packed f4
// channels {a,b,a^2+b^2,ab} -> ds_write_b128 stride-1; register prefetch of
// next stage's rows; H-blur q=lane>>3, run=lane&7, S0 = run<7 ? 7run : 47
// (no clamp in the 17-tap read loop; run 7 masks oo<2). Intra-wave LDS
// ordering is HW-guaranteed -> zero __syncthreads in the hot loop.
// No min-occupancy launch_bounds arg (r5/r6: forces spills).
// Deterministic reduction: per-wave partial -> finalize kernel -> d_out[0].

typedef float f4 __attribute__((ext_vector_type(4)));

#define W      1024
#define H      1024
#define NIMG   16
#define HALO   5
#define TW     64                  // input cols per wave tile (LDS slots)
#define TOW    54                  // output cols per wave tile
#define RPS    8                   // rows per stage
#define NSTG   4                   // stages per wave
#define TH     (RPS*NSTG)          // 32 output rows per wave
#define NTX    19                  // ceil(1024/54)
#define NTY    (H/TH)              // 32
#define WPB    8                   // waves per block (forces 8-wave residency)
#define BX     (WPB*64)            // 512 threads
#define NWAVE  (NTX*NTY*NIMG)      // 9728
#define NBLK   (NWAVE/WPB)         // 1216

template<bool INT>
__device__ __forceinline__ void pf_row(const float* __restrict__ p1,
                                       const float* __restrict__ p2,
                                       int j, int c, bool cOK,
                                       float& a, float& b)
{
    if (INT) {
        a = p1[(size_t)j * W + c];
        b = p2[(size_t)j * W + c];
    } else {
        const bool ok = cOK && ((unsigned)j < H);
        a = ok ? p1[(size_t)j * W + c] : 0.0f;
        b = ok ? p2[(size_t)j * W + c] : 0.0f;
    }
}

__device__ __forceinline__ f4 pack_ch(float a, float b)
{
    f4 v;
    v.x = a; v.y = b;
    v.z = fmaf(a, a, b * b);
    v.w = a * b;
    return v;
}

template<bool INT>
__device__ float wave_tile(const float* __restrict__ p1,
                           const float* __restrict__ p2,
                           const float* __restrict__ w,
                           int cb, int r0, int lane, int obase,
                           f4 (*lds)[TW])
{
    const int  c   = cb + lane;              // this lane's input col
    const bool cOK = INT || ((unsigned)c < W);

    // ring[1..10] <- rows r0-5 .. r0+4 (packed 4 channels)
    f4 ring[11];
#pragma unroll
    for (int k = 0; k < 10; ++k) {
        float a, b;
        pf_row<INT>(p1, p2, r0 - HALO + k, c, cOK, a, b);
        ring[k + 1] = pack_ch(a, b);
    }

    // H mapping: lane -> (staged row q, 7-col run); run 7 shifted to S0=47
    const int q   = lane >> 3;               // 0..7
    const int run = lane & 7;                // 0..7
    const int S0  = (run < 7) ? 7 * run : 47;

    // prefetch stage 0 rows
    float pa[RPS], pb[RPS];
#pragma unroll
    for (int rr = 0; rr < RPS; ++rr)
        pf_row<INT>(p1, p2, r0 + HALO + rr, c, cOK, pa[rr], pb[rr]);

    float tsum = 0.0f;

    for (int st = 0; st < NSTG; ++st) {
        // ---- V phase: consume prefetched rows, write own LDS slab ----
#pragma unroll
        for (int rr = 0; rr < RPS; ++rr) {
#pragma unroll
            for (int k = 0; k < 10; ++k) ring[k] = ring[k + 1];
            ring[10] = pack_ch(pa[rr], pb[rr]);

            f4 acc = w[5] * ring[5];
#pragma unroll
            for (int k = 0; k < 5; ++k)
                acc += w[k] * (ring[k] + ring[10 - k]);

            lds[rr][lane] = acc;
        }

        // ---- prefetch stage st+1 (latency hidden under H below) ----
        if (st + 1 < NSTG) {
#pragma unroll
            for (int rr = 0; rr < RPS; ++rr)
                pf_row<INT>(p1, p2, r0 + (st + 1) * RPS + HALO + rr, c, cOK,
                            pa[rr], pb[rr]);
        }

        // ---- H phase: row q, outputs S0..S0+6 (in-order DS => RAW safe) ----
        {
            f4 o[7] = {};
#pragma unroll
            for (int i = 0; i < 17; ++i) {           // S0+16 <= 63: no clamp
                const f4 u = lds[q][S0 + i];
#pragma unroll
                for (int oo = 0; oo < 7; ++oo) {
                    const int k = i - oo;
                    if (k >= 0 && k < 11)
                        o[oo] += w[k] * u;
                }
            }

            const float C1f = 0.0001f, C2f = 0.0009f;
#pragma unroll
            for (int oo = 0; oo < 7; ++oo) {
                const int rel = S0 + oo;
                // run 7 re-covers run 6's cols at oo<2 -> mask those
                const bool valid = ((run < 7) || (oo >= 2)) &&
                                   (INT || (obase + rel) < W);
                if (valid) {
                    const float m1 = o[oo].x, m2 = o[oo].y;
                    const float qq = o[oo].z, pp = o[oo].w;
                    const float mu12 = m1 * m2, m1s = m1 * m1, m2s = m2 * m2;
                    const float s12 = pp - mu12;
                    const float ssq = qq - m1s - m2s;
                    const float num = (2.f * mu12 + C1f) * (2.f * s12 + C2f);
                    const float den = (m1s + m2s + C1f) * (ssq + C2f);
                    tsum += num * __builtin_amdgcn_rcpf(den);
                }
            }
        }
    }
    return tsum;
}

__global__ __launch_bounds__(BX) void ssim_main(const float* __restrict__ img1,
                                                const float* __restrict__ img2,
                                                const float* __restrict__ win,
                                                float* __restrict__ partials)
{
    __shared__ f4 lds[WPB][RPS][TW];         // 8 x 8 KB private wave slabs

    const int t    = threadIdx.x;
    const int wid  = t >> 6;
    const int lane = t & 63;
    const int gw   = blockIdx.x * WPB + wid; // global wave id

    // gw -> (img, gy, tx); tx fastest so neighboring waves share halo in L2
    const int img = gw / (NTX * NTY);
    const int rem = gw - img * (NTX * NTY);
    const int gy  = rem / NTX;
    const int tx  = rem - gy * NTX;

    const int cb    = tx * TOW - HALO;       // input col of LDS slot 0
    const int obase = tx * TOW;              // abs col of output 0
    const int r0    = gy * TH;

    const float* __restrict__ p1 = img1 + (size_t)img * (size_t)(W * H);
    const float* __restrict__ p2 = img2 + (size_t)img * (size_t)(W * H);

    float w[11];
#pragma unroll
    for (int k = 0; k < 11; ++k)
        w[k] = __int_as_float(__builtin_amdgcn_readfirstlane(__float_as_int(win[k])));

    const bool interior = (cb >= 0) && (cb + TW <= W) &&
                          (r0 >= HALO) && (r0 + TH - 1 + HALO < H);

    float tsum = interior
               ? wave_tile<true >(p1, p2, w, cb, r0, lane, obase, lds[wid])
               : wave_tile<false>(p1, p2, w, cb, r0, lane, obase, lds[wid]);

    // wave-private reduction; one store per wave — still no barrier
#pragma unroll
    for (int off = 32; off > 0; off >>= 1)
        tsum += __shfl_down(tsum, off, 64);

    if (lane == 0)
        partials[gw] = tsum;
}

__global__ __launch_bounds__(256) void ssim_finalize(const float* __restrict__ partials,
                                                     float* __restrict__ out)
{
    double s = 0.0;
    for (int i = threadIdx.x; i < NWAVE; i += 256) s += (double)partials[i];
#pragma unroll
    for (int off = 32; off > 0; off >>= 1)
        s += __shfl_down(s, off, 64);

    __shared__ double ws[4];
    if ((threadIdx.x & 63) == 0) ws[threadIdx.x >> 6] = s;
    __syncthreads();
    if (threadIdx.x == 0) {
        const double tt = ws[0] + ws[1] + ws[2] + ws[3];
        out[0] = (float)(tt / (double)((size_t)NIMG * W * H));
    }
}

extern "C" void kernel_launch(void* const* d_in, const int* in_sizes, int n_in,
                              void* d_out, int out_size, void* d_ws, size_t ws_size,
                              hipStream_t stream)
{
    const float* img1 = (const float*)d_in[0];
    const float* img2 = (const float*)d_in[1];
    const float* win  = (const float*)d_in[2];
    float* partials   = (float*)d_ws;
    float* out        = (float*)d_out;

    ssim_main<<<NBLK, BX, 0, stream>>>(img1, img2, win, partials);
    ssim_finalize<<<1, 256, 0, stream>>>(partials, out);
}

// Round 18
// 64.479 us; speedup vs baseline: 1.0357x; 1.0357x over previous
//
#include <hip/hip_runtime.h>

// SSIM fused: [16,1,1024,1024] fp32, 11-tap separable Gaussian.
// r12 structure (barrier-free wave-private 64x64 tiles, register prefetch,
// 4 waves x 8 KB LDS slabs) + PACKED FP32 math: V-blur and H-blur cores use
// v_pk_{mul,add,fma}_f32 on float2 channel pairs {a,b} and {a^2+b^2, ab},
// halving VALU instruction count (~88 fma/px -> ~44 pk/px). Weights are
// pre-broadcast float2 {w,w}. H mapping: q=lane>>3, run=lane&7,
// S0 = run<7 ? 7*run : 47 (no clamp; run 7 masks oo<2).
// No min-occupancy launch_bounds arg (r5/r6: forces spills).
// Deterministic reduction: per-wave partial -> finalize kernel -> d_out[0].

typedef float f2 __attribute__((ext_vector_type(2)));
typedef float f4 __attribute__((ext_vector_type(4)));

#define W      1024
#define H      1024
#define NIMG   16
#define HALO   5
#define TW     64                  // input cols per wave tile (LDS slots)
#define TOW    54                  // output cols per wave tile
#define RPS    8                   // rows per stage
#define NSTG   8                   // stages per wave
#define TH     (RPS*NSTG)          // 64 output rows per wave
#define NTX    19                  // ceil(1024/54)
#define NTY    (H/TH)              // 16
#define WPB    4                   // waves per block
#define BX     (WPB*64)            // 256 threads
#define NWAVE  (NTX*NTY*NIMG)      // 4864
#define NBLK   (NWAVE/WPB)         // 1216

__device__ __forceinline__ f2 pk_add(f2 a, f2 b)
{
    f2 d;
    asm("v_pk_add_f32 %0, %1, %2" : "=v"(d) : "v"(a), "v"(b));
    return d;
}
__device__ __forceinline__ f2 pk_mul(f2 a, f2 b)
{
    f2 d;
    asm("v_pk_mul_f32 %0, %1, %2" : "=v"(d) : "v"(a), "v"(b));
    return d;
}
__device__ __forceinline__ void pk_fma(f2& acc, f2 a, f2 b)
{
    asm("v_pk_fma_f32 %0, %1, %2, %0" : "+v"(acc) : "v"(a), "v"(b));
}

template<bool INT>
__device__ __forceinline__ void pf_row(const float* __restrict__ p1,
                                       const float* __restrict__ p2,
                                       int j, int c, bool cOK,
                                       float& a, float& b)
{
    if (INT) {
        a = p1[(size_t)j * W + c];
        b = p2[(size_t)j * W + c];
    } else {
        const bool ok = cOK && ((unsigned)j < H);
        a = ok ? p1[(size_t)j * W + c] : 0.0f;
        b = ok ? p2[(size_t)j * W + c] : 0.0f;
    }
}

template<bool INT>
__device__ float wave_tile(const float* __restrict__ p1,
                           const float* __restrict__ p2,
                           const f2* __restrict__ w2,
                           int cb, int r0, int lane, int obase,
                           f4 (*lds)[TW])
{
    const int  c   = cb + lane;              // this lane's input col
    const bool cOK = INT || ((unsigned)c < W);

    // rings of 11 rows: AB = {a,b}, QP = {a^2+b^2, a*b}
    f2 rAB[11], rQP[11];
#pragma unroll
    for (int k = 0; k < 10; ++k) {
        float a, b;
        pf_row<INT>(p1, p2, r0 - HALO + k, c, cOK, a, b);
        rAB[k + 1].x = a;              rAB[k + 1].y = b;
        rQP[k + 1].x = fmaf(a, a, b * b); rQP[k + 1].y = a * b;
    }

    // H mapping: lane -> (staged row q, 7-col run); run 7 shifted to S0=47
    const int q   = lane >> 3;               // 0..7
    const int run = lane & 7;                // 0..7
    const int S0  = (run < 7) ? 7 * run : 47;

    // prefetch stage 0 rows
    float pa[RPS], pb[RPS];
#pragma unroll
    for (int rr = 0; rr < RPS; ++rr)
        pf_row<INT>(p1, p2, r0 + HALO + rr, c, cOK, pa[rr], pb[rr]);

    float tsum = 0.0f;

    for (int st = 0; st < NSTG; ++st) {
        // ---- V phase: consume prefetched rows, write own LDS slab ----
#pragma unroll
        for (int rr = 0; rr < RPS; ++rr) {
#pragma unroll
            for (int k = 0; k < 10; ++k) { rAB[k] = rAB[k + 1]; rQP[k] = rQP[k + 1]; }
            {
                const float a = pa[rr], b = pb[rr];
                rAB[10].x = a;               rAB[10].y = b;
                rQP[10].x = fmaf(a, a, b * b); rQP[10].y = a * b;
            }

            f2 vAB = pk_mul(w2[5], rAB[5]);
            f2 vQP = pk_mul(w2[5], rQP[5]);
#pragma unroll
            for (int k = 0; k < 5; ++k) {
                pk_fma(vAB, w2[k], pk_add(rAB[k], rAB[10 - k]));
                pk_fma(vQP, w2[k], pk_add(rQP[k], rQP[10 - k]));
            }

            f4 v;
            v.x = vAB.x; v.y = vAB.y; v.z = vQP.x; v.w = vQP.y;
            lds[rr][lane] = v;
        }

        // ---- prefetch stage st+1 (latency hidden under H below) ----
        if (st + 1 < NSTG) {
#pragma unroll
            for (int rr = 0; rr < RPS; ++rr)
                pf_row<INT>(p1, p2, r0 + (st + 1) * RPS + HALO + rr, c, cOK,
                            pa[rr], pb[rr]);
        }

        // ---- H phase: row q, outputs S0..S0+6 (in-order DS => RAW safe) ----
        {
            f2 oAB[7] = {}, oQP[7] = {};
#pragma unroll
            for (int i = 0; i < 17; ++i) {           // S0+16 <= 63: no clamp
                const f4 u = lds[q][S0 + i];
                const f2 uAB = __builtin_shufflevector(u, u, 0, 1);
                const f2 uQP = __builtin_shufflevector(u, u, 2, 3);
#pragma unroll
                for (int oo = 0; oo < 7; ++oo) {
                    const int k = i - oo;
                    if (k >= 0 && k < 11) {
                        pk_fma(oAB[oo], w2[k], uAB);
                        pk_fma(oQP[oo], w2[k], uQP);
                    }
                }
            }

            const float C1f = 0.0001f, C2f = 0.0009f;
#pragma unroll
            for (int oo = 0; oo < 7; ++oo) {
                const int rel = S0 + oo;
                // run 7 re-covers run 6's cols at oo<2 -> mask those
                const bool valid = ((run < 7) || (oo >= 2)) &&
                                   (INT || (obase + rel) < W);
                if (valid) {
                    const float m1 = oAB[oo].x, m2 = oAB[oo].y;
                    const float qq = oQP[oo].x, pp = oQP[oo].y;
                    const float mu12 = m1 * m2, m1s = m1 * m1, m2s = m2 * m2;
                    const float s12 = pp - mu12;
                    const float ssq = qq - m1s - m2s;
                    const float num = (2.f * mu12 + C1f) * (2.f * s12 + C2f);
                    const float den = (m1s + m2s + C1f) * (ssq + C2f);
                    tsum += num * __builtin_amdgcn_rcpf(den);
                }
            }
        }
    }
    return tsum;
}

__global__ __launch_bounds__(BX) void ssim_main(const float* __restrict__ img1,
                                                const float* __restrict__ img2,
                                                const float* __restrict__ win,
                                                float* __restrict__ partials)
{
    __shared__ f4 lds[WPB][RPS][TW];         // 4 x 8 KB private wave slabs

    const int t    = threadIdx.x;
    const int wid  = t >> 6;
    const int lane = t & 63;
    const int gw   = blockIdx.x * WPB + wid; // global wave id

    // gw -> (img, gy, tx); tx fastest so neighboring waves share halo in L2
    const int img = gw / (NTX * NTY);
    const int rem = gw - img * (NTX * NTY);
    const int gy  = rem / NTX;
    const int tx  = rem - gy * NTX;

    const int cb    = tx * TOW - HALO;       // input col of LDS slot 0
    const int obase = tx * TOW;              // abs col of output 0
    const int r0    = gy * TH;

    const float* __restrict__ p1 = img1 + (size_t)img * (size_t)(W * H);
    const float* __restrict__ p2 = img2 + (size_t)img * (size_t)(W * H);

    f2 w2[11];
#pragma unroll
    for (int k = 0; k < 11; ++k) {
        const float wk =
            __int_as_float(__builtin_amdgcn_readfirstlane(__float_as_int(win[k])));
        w2[k].x = wk; w2[k].y = wk;
    }

    const bool interior = (cb >= 0) && (cb + TW <= W) &&
                          (r0 >= HALO) && (r0 + TH - 1 + HALO < H);

    float tsum = interior
               ? wave_tile<true >(p1, p2, w2, cb, r0, lane, obase, lds[wid])
               : wave_tile<false>(p1, p2, w2, cb, r0, lane, obase, lds[wid]);

    // wave-private reduction; one store per wave — still no barrier
#pragma unroll
    for (int off = 32; off > 0; off >>= 1)
        tsum += __shfl_down(tsum, off, 64);

    if (lane == 0)
        partials[gw] = tsum;
}

__global__ __launch_bounds__(256) void ssim_finalize(const float* __restrict__ partials,
                                                     float* __restrict__ out)
{
    double s = 0.0;
    for (int i = threadIdx.x; i < NWAVE; i += 256) s += (double)partials[i];
#pragma unroll
    for (int off = 32; off > 0; off >>= 1)
        s += __shfl_down(s, off, 64);

    __shared__ double ws[4];
    if ((threadIdx.x & 63) == 0) ws[threadIdx.x >> 6] = s;
    __syncthreads();
    if (threadIdx.x == 0) {
        const double tt = ws[0] + ws[1] + ws[2] + ws[3];
        out[0] = (float)(tt / (double)((size_t)NIMG * W * H));
    }
}

extern "C" void kernel_launch(void* const* d_in, const int* in_sizes, int n_in,
                              void* d_out, int out_size, void* d_ws, size_t ws_size,
                              hipStream_t stream)
{
    const float* img1 = (const float*)d_in[0];
    const float* img2 = (const float*)d_in[1];
    const float* win  = (const float*)d_in[2];
    float* partials   = (float*)d_ws;
    float* out        = (float*)d_out;

    ssim_main<<<NBLK, BX, 0, stream>>>(img1, img2, win, partials);
    ssim_finalize<<<1, 256, 0, stream>>>(partials, out);
}